// Round 1
// baseline (92.320 us; speedup 1.0000x reference)
//
#include <hip/hip_runtime.h>

#define NQ 4
#define DIM 16   // 2^NQ

// CNOT ring with compile-time range R so all register-array indices fold.
template<int R>
__device__ __forceinline__ void cnot_ring(float (&sr)[DIM], float (&si)[DIM]) {
#pragma unroll
    for (int q = 0; q < NQ; q++) {
        const int t  = (q + R) % NQ;
        const int cs = 1 << (NQ - 1 - q);   // control bit stride
        const int ts = 1 << (NQ - 1 - t);   // target bit stride
#pragma unroll
        for (int i = 0; i < DIM; i++) {
            if ((i & cs) && !(i & ts)) {
                const int j = i | ts;
                float tr = sr[i]; sr[i] = sr[j]; sr[j] = tr;
                float ti = si[i]; si[i] = si[j]; si[j] = ti;
            }
        }
    }
}

__global__ __launch_bounds__(256) void qsim_kernel(
    const float* __restrict__ inputs,   // [B, 4]
    const float* __restrict__ weights,  // [L, 4, 3]
    float* __restrict__ out,            // [4, B]
    int B, int L)
{
    const int b = blockIdx.x * blockDim.x + threadIdx.x;
    if (b >= B) return;

    // coalesced 16B load of this sample's 4 angles
    const float4 x4 = reinterpret_cast<const float4*>(inputs)[b];
    const float xs[NQ] = {x4.x, x4.y, x4.z, x4.w};

    // |0000> state in registers
    float sr[DIM], si[DIM];
#pragma unroll
    for (int i = 0; i < DIM; i++) { sr[i] = 0.0f; si[i] = 0.0f; }
    sr[0] = 1.0f;

    // ---- AngleEmbedding: RY(x_q) on wire q.  gate = [[c,-s],[s,c]], th = x/2
#pragma unroll
    for (int q = 0; q < NQ; q++) {
        float s, c;
        __sincosf(0.5f * xs[q], &s, &c);
        const int st = 1 << (NQ - 1 - q);
#pragma unroll
        for (int i = 0; i < DIM; i++) {
            if (i & st) continue;
            const int j = i | st;
            const float r0 = sr[i], i0 = si[i], r1 = sr[j], i1 = si[j];
            sr[i] = c * r0 - s * r1;  si[i] = c * i0 - s * i1;
            sr[j] = s * r0 + c * r1;  si[j] = s * i0 + c * i1;
        }
    }

    // ---- StronglyEntanglingLayers
    for (int l = 0; l < L; l++) {
        const int r = l % (NQ - 1) + 1;
#pragma unroll
        for (int q = 0; q < NQ; q++) {
            const float phi = weights[(l * NQ + q) * 3 + 0];
            const float th  = weights[(l * NQ + q) * 3 + 1];
            const float om  = weights[(l * NQ + q) * 3 + 2];
            float stg, ctg;  __sincosf(0.5f * th, &stg, &ctg);
            float sp, cp;    __sincosf(0.5f * (phi + om), &sp, &cp);
            float sm, cm;    __sincosf(0.5f * (phi - om), &sm, &cm);
            // Rot = RZ(om) RY(th) RZ(phi):
            // g00 = e^{-i(phi+om)/2} c ; g01 = -e^{ i(phi-om)/2} s
            // g10 = e^{-i(phi-om)/2} s ; g11 =  e^{ i(phi+om)/2} c
            const float g00r =  cp * ctg, g00i = -sp * ctg;
            const float g01r = -cm * stg, g01i = -sm * stg;
            const float g10r =  cm * stg, g10i = -sm * stg;
            const float g11r =  cp * ctg, g11i =  sp * ctg;
            const int st = 1 << (NQ - 1 - q);
#pragma unroll
            for (int i = 0; i < DIM; i++) {
                if (i & st) continue;
                const int j = i | st;
                const float r0 = sr[i], i0 = si[i], r1 = sr[j], i1 = si[j];
                sr[i] = g00r * r0 - g00i * i0 + g01r * r1 - g01i * i1;
                si[i] = g00r * i0 + g00i * r0 + g01r * i1 + g01i * r1;
                sr[j] = g10r * r0 - g10i * i0 + g11r * r1 - g11i * i1;
                si[j] = g10r * i0 + g10i * r0 + g11r * i1 + g11i * r1;
            }
        }
        switch (r) {
            case 1: cnot_ring<1>(sr, si); break;
            case 2: cnot_ring<2>(sr, si); break;
            default: cnot_ring<3>(sr, si); break;
        }
    }

    // ---- probabilities and <Z_q>
    float p[DIM];
#pragma unroll
    for (int i = 0; i < DIM; i++) p[i] = sr[i] * sr[i] + si[i] * si[i];
#pragma unroll
    for (int q = 0; q < NQ; q++) {
        const int st = 1 << (NQ - 1 - q);
        float e = 0.0f;
#pragma unroll
        for (int i = 0; i < DIM; i++) e += (i & st) ? -p[i] : p[i];
        out[(size_t)q * B + b] = e;
    }
}

extern "C" void kernel_launch(void* const* d_in, const int* in_sizes, int n_in,
                              void* d_out, int out_size, void* d_ws, size_t ws_size,
                              hipStream_t stream) {
    const float* inputs  = (const float*)d_in[0];
    const float* weights = (const float*)d_in[1];
    float* out = (float*)d_out;
    const int B = in_sizes[0] / NQ;
    const int L = in_sizes[1] / (NQ * 3);
    const int threads = 256;
    const int blocks = (B + threads - 1) / threads;
    qsim_kernel<<<blocks, threads, 0, stream>>>(inputs, weights, out, B, L);
}

// Round 2
// 68.529 us; speedup vs baseline: 1.3472x; 1.3472x over previous
//
#include <hip/hip_runtime.h>

#define NQ 4
#define DIM 16   // 2^NQ

// ---------------- Fast path: L == 1 (ring range r = 1) ----------------
// Product-state algebra: z_q = cos(th_q) cos(x_q) - sin(th_q) cos(phi_q) sin(x_q)
// <Z0> = z1 z2 z3 ; <Z1> = z0 z1 ; <Z2> = z0 z1 z2 ; <Z3> = z0 z1 z2 z3
__global__ __launch_bounds__(256) void qsim_l1_kernel(
    const float* __restrict__ inputs,   // [B, 4]
    const float* __restrict__ weights,  // [1, 4, 3]
    float* __restrict__ out,            // [4, B]
    int B)
{
    // uniform per-qubit constants (weights are batch-independent)
    float A[NQ], Bc[NQ];
#pragma unroll
    for (int q = 0; q < NQ; q++) {
        const float phi = weights[q * 3 + 0];
        const float th  = weights[q * 3 + 1];
        float sth, cth;  __sincosf(th, &sth, &cth);
        A[q]  = cth;
        Bc[q] = -sth * __cosf(phi);
    }

    const int t = blockIdx.x * blockDim.x + threadIdx.x;   // handles 4 samples
    const int nquad = B >> 2;
    if (t >= nquad) return;

    // 4 samples = 16 contiguous floats
    const float4* in4 = reinterpret_cast<const float4*>(inputs) + (size_t)t * 4;
    float4 o[NQ];   // o[q].{x,y,z,w} = outputs for samples 4t..4t+3

#pragma unroll
    for (int s = 0; s < 4; s++) {
        const float4 x = in4[s];
        const float xs[NQ] = {x.x, x.y, x.z, x.w};
        float z[NQ];
#pragma unroll
        for (int q = 0; q < NQ; q++) {
            float sx, cx;
            __sincosf(xs[q], &sx, &cx);
            z[q] = A[q] * cx + Bc[q] * sx;
        }
        const float z12  = z[1] * z[2];
        const float z01  = z[0] * z[1];
        const float z012 = z01 * z[2];
        const float e0 = z12 * z[3];
        const float e1 = z01;
        const float e2 = z012;
        const float e3 = z012 * z[3];
        if (s == 0) { o[0].x = e0; o[1].x = e1; o[2].x = e2; o[3].x = e3; }
        if (s == 1) { o[0].y = e0; o[1].y = e1; o[2].y = e2; o[3].y = e3; }
        if (s == 2) { o[0].z = e0; o[1].z = e1; o[2].z = e2; o[3].z = e3; }
        if (s == 3) { o[0].w = e0; o[1].w = e1; o[2].w = e2; o[3].w = e3; }
    }

#pragma unroll
    for (int q = 0; q < NQ; q++) {
        reinterpret_cast<float4*>(out + (size_t)q * B)[t] = o[q];
    }
}

// ---------------- General fallback (any L) ----------------
template<int R>
__device__ __forceinline__ void cnot_ring(float (&sr)[DIM], float (&si)[DIM]) {
#pragma unroll
    for (int q = 0; q < NQ; q++) {
        const int tt = (q + R) % NQ;
        const int cs = 1 << (NQ - 1 - q);
        const int ts = 1 << (NQ - 1 - tt);
#pragma unroll
        for (int i = 0; i < DIM; i++) {
            if ((i & cs) && !(i & ts)) {
                const int j = i | ts;
                float tr = sr[i]; sr[i] = sr[j]; sr[j] = tr;
                float ti = si[i]; si[i] = si[j]; si[j] = ti;
            }
        }
    }
}

__global__ __launch_bounds__(256) void qsim_kernel(
    const float* __restrict__ inputs,
    const float* __restrict__ weights,
    float* __restrict__ out,
    int B, int L)
{
    const int b = blockIdx.x * blockDim.x + threadIdx.x;
    if (b >= B) return;

    const float4 x4 = reinterpret_cast<const float4*>(inputs)[b];
    const float xs[NQ] = {x4.x, x4.y, x4.z, x4.w};

    float sr[DIM], si[DIM];
#pragma unroll
    for (int i = 0; i < DIM; i++) { sr[i] = 0.0f; si[i] = 0.0f; }
    sr[0] = 1.0f;

#pragma unroll
    for (int q = 0; q < NQ; q++) {
        float s, c;
        __sincosf(0.5f * xs[q], &s, &c);
        const int st = 1 << (NQ - 1 - q);
#pragma unroll
        for (int i = 0; i < DIM; i++) {
            if (i & st) continue;
            const int j = i | st;
            const float r0 = sr[i], i0 = si[i], r1 = sr[j], i1 = si[j];
            sr[i] = c * r0 - s * r1;  si[i] = c * i0 - s * i1;
            sr[j] = s * r0 + c * r1;  si[j] = s * i0 + c * i1;
        }
    }

    for (int l = 0; l < L; l++) {
        const int r = l % (NQ - 1) + 1;
#pragma unroll
        for (int q = 0; q < NQ; q++) {
            const float phi = weights[(l * NQ + q) * 3 + 0];
            const float th  = weights[(l * NQ + q) * 3 + 1];
            const float om  = weights[(l * NQ + q) * 3 + 2];
            float stg, ctg;  __sincosf(0.5f * th, &stg, &ctg);
            float sp, cp;    __sincosf(0.5f * (phi + om), &sp, &cp);
            float sm, cm;    __sincosf(0.5f * (phi - om), &sm, &cm);
            const float g00r =  cp * ctg, g00i = -sp * ctg;
            const float g01r = -cm * stg, g01i = -sm * stg;
            const float g10r =  cm * stg, g10i = -sm * stg;
            const float g11r =  cp * ctg, g11i =  sp * ctg;
            const int st = 1 << (NQ - 1 - q);
#pragma unroll
            for (int i = 0; i < DIM; i++) {
                if (i & st) continue;
                const int j = i | st;
                const float r0 = sr[i], i0 = si[i], r1 = sr[j], i1 = si[j];
                sr[i] = g00r * r0 - g00i * i0 + g01r * r1 - g01i * i1;
                si[i] = g00r * i0 + g00i * r0 + g01r * i1 + g01i * r1;
                sr[j] = g10r * r0 - g10i * i0 + g11r * r1 - g11i * i1;
                si[j] = g10r * i0 + g10i * r0 + g11r * i1 + g11i * r1;
            }
        }
        switch (r) {
            case 1: cnot_ring<1>(sr, si); break;
            case 2: cnot_ring<2>(sr, si); break;
            default: cnot_ring<3>(sr, si); break;
        }
    }

    float p[DIM];
#pragma unroll
    for (int i = 0; i < DIM; i++) p[i] = sr[i] * sr[i] + si[i] * si[i];
#pragma unroll
    for (int q = 0; q < NQ; q++) {
        const int st = 1 << (NQ - 1 - q);
        float e = 0.0f;
#pragma unroll
        for (int i = 0; i < DIM; i++) e += (i & st) ? -p[i] : p[i];
        out[(size_t)q * B + b] = e;
    }
}

extern "C" void kernel_launch(void* const* d_in, const int* in_sizes, int n_in,
                              void* d_out, int out_size, void* d_ws, size_t ws_size,
                              hipStream_t stream) {
    const float* inputs  = (const float*)d_in[0];
    const float* weights = (const float*)d_in[1];
    float* out = (float*)d_out;
    const int B = in_sizes[0] / NQ;
    const int L = in_sizes[1] / (NQ * 3);
    const int threads = 256;
    if (L == 1 && (B & 3) == 0) {
        const int nquad = B >> 2;
        const int blocks = (nquad + threads - 1) / threads;
        qsim_l1_kernel<<<blocks, threads, 0, stream>>>(inputs, weights, out, B);
    } else {
        const int blocks = (B + threads - 1) / threads;
        qsim_kernel<<<blocks, threads, 0, stream>>>(inputs, weights, out, B, L);
    }
}